// Round 11
// baseline (68.069 us; speedup 1.0000x reference)
//
#include <hip/hip_runtime.h>
#include <math.h>

// Problem constants
#define NB 128     // batch
#define NR 1152    // routes
#define NC 10      // capsules
#define NCHK 24    // chunks per capsule (route-chunks of 48)

typedef __attribute__((ext_vector_type(8))) short bf16x8;
typedef __attribute__((ext_vector_type(16))) float f32x16;

__device__ __forceinline__ unsigned pk_bf16(float a, float b) {
    unsigned r;
    asm("v_cvt_pk_bf16_f32 %0, %1, %2" : "=v"(r) : "v"(a), "v"(b));
    return r;
}

// ------------------------------------------------------------------
// route_mainloop: on-the-fly bf16x3 + 32x32x16 MFMA pred + route reduce.
// A = W (M=o), B = x (N=b). C: col(l&31)=b, row(reg&3)+8*(reg>>2)+4*hi1=o.
// MODE 0: uniform sum (MFMA-chained); x direct (scattered); owner lanes
//         write xts bf16 hi/lo planes ((h*12+rr)%10 == c).
// MODE 1: x fragments from xts (coalesced, MFMA-ready); d = pred.ov,
//         e = exp(d-20), Z += e, acc += e*pred.
// ------------------------------------------------------------------
template<int MODE>
__device__ __forceinline__ void route_mainloop(
    const float* __restrict__ x, const float* __restrict__ W,
    uint4* __restrict__ xt4,
    int c, int r0, int bp, int lo5, int hi1,
    const float (&ov0)[16], const float (&ov1)[16],
    f32x16& acc0, f32x16& acc1, float& Z0, float& Z1)
{
    f32x16 zz;
#pragma unroll
    for (int j = 0; j < 16; ++j) { acc0[j] = 0.f; acc1[j] = 0.f; zz[j] = 0.f; }
    Z0 = 0.f; Z1 = 0.f;

    // W element (r, i=hi1*8+j, o=lo5)
    const float* wb = W + ((size_t)(c * NR + r0) * 16 + hi1 * 8) * 32 + lo5;
    const float* xp0 = nullptr, * xp1 = nullptr;
    if (MODE == 0) {
        xp0 = x + ((size_t)(bp * 64 + lo5) * NR + r0) * 16 + hi1 * 8;
        xp1 = x + ((size_t)(bp * 64 + 32 + lo5) * NR + r0) * 16 + hi1 * 8;
    }
    const int bq0 = bp * 64 + lo5, bq1 = bq0 + 32;

    for (int rr = 0; rr < 12; ++rr) {
        // ---- W fragment: 8 lane-coalesced f32 -> hi/lo bf16 planes ----
        float wv[8];
#pragma unroll
        for (int j = 0; j < 8; ++j) wv[j] = wb[(size_t)rr * 512 + j * 32];
        union U { uint4 q; unsigned u[4]; bf16x8 v; };
        U Ah, Al, Xh0, Xl0, Xh1, Xl1;
#pragma unroll
        for (int j = 0; j < 4; ++j) Ah.u[j] = pk_bf16(wv[2*j], wv[2*j+1]);
#pragma unroll
        for (int j = 0; j < 4; ++j) {
            float g0 = __uint_as_float(Ah.u[j] << 16);
            float g1 = __uint_as_float(Ah.u[j] & 0xffff0000u);
            Al.u[j] = pk_bf16(wv[2*j] - g0, wv[2*j+1] - g1);
        }
        // ---- x fragments ----
        const size_t rb4 = ((size_t)((r0 + rr) * 2 + hi1) * 2) * 128;
        if (MODE == 0) {
            float4 u0 = *(const float4*)(xp0 + rr * 16);
            float4 u1 = *(const float4*)(xp0 + rr * 16 + 4);
            float4 v0 = *(const float4*)(xp1 + rr * 16);
            float4 v1 = *(const float4*)(xp1 + rr * 16 + 4);
            float xv0[8] = {u0.x,u0.y,u0.z,u0.w, u1.x,u1.y,u1.z,u1.w};
            float xv1[8] = {v0.x,v0.y,v0.z,v0.w, v1.x,v1.y,v1.z,v1.w};
#pragma unroll
            for (int j = 0; j < 4; ++j) Xh0.u[j] = pk_bf16(xv0[2*j], xv0[2*j+1]);
#pragma unroll
            for (int j = 0; j < 4; ++j) {
                float g0 = __uint_as_float(Xh0.u[j] << 16);
                float g1 = __uint_as_float(Xh0.u[j] & 0xffff0000u);
                Xl0.u[j] = pk_bf16(xv0[2*j] - g0, xv0[2*j+1] - g1);
            }
#pragma unroll
            for (int j = 0; j < 4; ++j) Xh1.u[j] = pk_bf16(xv1[2*j], xv1[2*j+1]);
#pragma unroll
            for (int j = 0; j < 4; ++j) {
                float g0 = __uint_as_float(Xh1.u[j] << 16);
                float g1 = __uint_as_float(Xh1.u[j] & 0xffff0000u);
                Xl1.u[j] = pk_bf16(xv1[2*j] - g0, xv1[2*j+1] - g1);
            }
            // distributed xts write: this block owns routes (h*12+rr)%10 == c
            // (h*12+rr == local route index r0+rr - rch*48 ... ownership key
            //  is (r0+rr) mod 10 vs c via (h*12+rr)%10, matching round 8/10)
            if ((((r0 + rr) % 48) % 10) == c) {
                xt4[rb4 + bq0]       = Xh0.q;
                xt4[rb4 + 128 + bq0] = Xl0.q;
                xt4[rb4 + bq1]       = Xh1.q;
                xt4[rb4 + 128 + bq1] = Xl1.q;
            }
        } else {
            Xh0.q = xt4[rb4 + bq0];
            Xl0.q = xt4[rb4 + 128 + bq0];
            Xh1.q = xt4[rb4 + bq1];
            Xl1.q = xt4[rb4 + 128 + bq1];
        }

        if (MODE == 0) {
            acc0 = __builtin_amdgcn_mfma_f32_32x32x16_bf16(Ah.v, Xh0.v, acc0, 0, 0, 0);
            acc0 = __builtin_amdgcn_mfma_f32_32x32x16_bf16(Al.v, Xh0.v, acc0, 0, 0, 0);
            acc0 = __builtin_amdgcn_mfma_f32_32x32x16_bf16(Ah.v, Xl0.v, acc0, 0, 0, 0);
            acc1 = __builtin_amdgcn_mfma_f32_32x32x16_bf16(Ah.v, Xh1.v, acc1, 0, 0, 0);
            acc1 = __builtin_amdgcn_mfma_f32_32x32x16_bf16(Al.v, Xh1.v, acc1, 0, 0, 0);
            acc1 = __builtin_amdgcn_mfma_f32_32x32x16_bf16(Ah.v, Xl1.v, acc1, 0, 0, 0);
        } else {
            f32x16 q0, q1;
            q0 = __builtin_amdgcn_mfma_f32_32x32x16_bf16(Ah.v, Xh0.v, zz, 0, 0, 0);
            q1 = __builtin_amdgcn_mfma_f32_32x32x16_bf16(Ah.v, Xh1.v, zz, 0, 0, 0);
            q0 = __builtin_amdgcn_mfma_f32_32x32x16_bf16(Al.v, Xh0.v, q0, 0, 0, 0);
            q1 = __builtin_amdgcn_mfma_f32_32x32x16_bf16(Al.v, Xh1.v, q1, 0, 0, 0);
            q0 = __builtin_amdgcn_mfma_f32_32x32x16_bf16(Ah.v, Xl0.v, q0, 0, 0, 0);
            q1 = __builtin_amdgcn_mfma_f32_32x32x16_bf16(Ah.v, Xl1.v, q1, 0, 0, 0);
            float d0 = 0.f, d1 = 0.f;
#pragma unroll
            for (int j = 0; j < 16; ++j) {
                d0 = fmaf(q0[j], ov0[j], d0);
                d1 = fmaf(q1[j], ov1[j], d1);
            }
            d0 += __shfl_xor(d0, 32);
            d1 += __shfl_xor(d1, 32);
            float e0 = __expf(d0 - 20.0f);
            float e1 = __expf(d1 - 20.0f);
            Z0 += e0; Z1 += e1;
#pragma unroll
            for (int j = 0; j < 16; ++j) {
                acc0[j] = fmaf(e0, q0[j], acc0[j]);
                acc1[j] = fmaf(e1, q1[j], acc1[j]);
            }
        }
    }
}

// ------------------------------------------------------------------
// chunk_atomic_add: 8-wave XOR-swizzled LDS merge of the block's chunk,
// then agent-scope atomicAdd into the per-capsule accumulator (sc 16KB,
// zc 512B). Proven in round 10.
// ------------------------------------------------------------------
template<int WITHZ>
__device__ __forceinline__ void chunk_atomic_add(
    const f32x16& acc0, const f32x16& acc1, float Z0, float Z1,
    int t, int l, int h, int bp, int lo5, int hi1,
    float* lds, float* __restrict__ sc, float* __restrict__ zc)
{
    const int b0 = bp * 64 + lo5, b1 = b0 + 32;
    __syncthreads();
#pragma unroll
    for (int j = 0; j < 16; ++j) {
        int orow = (j & 3) + 8 * (j >> 2) + 4 * hi1;
        lds[h * 4096 + b0 * 32 + (orow ^ lo5)] = acc0[j];
        lds[h * 4096 + b1 * 32 + (orow ^ lo5)] = acc1[j];
    }
    __syncthreads();
    for (int idx = t; idx < 4096; idx += 512) {
        int b = idx >> 5, o = idx & 31;
        float s = 0.f;
#pragma unroll
        for (int hh = 0; hh < 4; ++hh)
            s += lds[hh * 4096 + b * 32 + (o ^ (b & 31))];
        (void)__hip_atomic_fetch_add(sc + idx, s, __ATOMIC_RELAXED,
                                     __HIP_MEMORY_SCOPE_AGENT);
    }
    if (WITHZ) {
        __syncthreads();
        if (l < 32) {
            lds[h * 128 + bp * 64 + lo5] = Z0;
            lds[h * 128 + bp * 64 + 32 + lo5] = Z1;
        }
        __syncthreads();
        if (t < 128) {
            float z = lds[t] + lds[128 + t] + lds[256 + t] + lds[384 + t];
            (void)__hip_atomic_fetch_add(zc + t, z, __ATOMIC_RELAXED,
                                         __HIP_MEMORY_SCOPE_AGENT);
        }
    }
}

// ------------------------------------------------------------------
// merge_squash: read the 16KB per-capsule sum (+512B Z), normalize,
// squash over batch. Leaves squashed out staged in lds[b*33+o] and the
// factor in lds[5008+o]; sv[k] holds this thread's pre-factor values.
// LDS: out 0..4224 | pn 4480..5008 | f 5008..5040 | z 5120..5248
// ------------------------------------------------------------------
template<int M, bool ATOM>
__device__ __forceinline__ void merge_squash(
    const float* __restrict__ sc, const float* __restrict__ zc,
    int t, float* lds, float (&sv)[8])
{
    if (M >= 1 && t < NB) {
        float z = ATOM ? __hip_atomic_load(zc + t, __ATOMIC_RELAXED,
                                           __HIP_MEMORY_SCOPE_AGENT)
                       : zc[t];
        lds[5120 + t] = z;
    }
    __syncthreads();
    float pn = 0.f;
#pragma unroll
    for (int k = 0; k < 8; ++k) {
        int idx = t + 512 * k;
        float s = ATOM ? __hip_atomic_load(sc + idx, __ATOMIC_RELAXED,
                                           __HIP_MEMORY_SCOPE_AGENT)
                       : sc[idx];
        float v = (M == 0) ? s * (1.0f / 1152.0f) : s / lds[5120 + (idx >> 5)];
        sv[k] = v;
        pn = fmaf(v, v, pn);
        lds[(idx >> 5) * 33 + (idx & 31)] = v;
    }
    lds[4480 + (t >> 5) * 33 + (t & 31)] = pn;
    __syncthreads();
    if (t < 32) {
        float n2 = 0.f;
#pragma unroll
        for (int m = 0; m < 16; ++m) n2 += lds[4480 + m * 33 + t];
        lds[5008 + t] = sqrtf(n2) / (1.0f + n2);   // (n2/(1+n2))/sqrt(n2)
    }
    __syncthreads();
}

// ------------------------------------------------------------------
// pass0_k: uniform pass. Mainloop MODE 0 (+xts emission) + atomicAdd of
// chunk partial into sb0. No merger: fused12_k merges sb0 redundantly.
// ------------------------------------------------------------------
__global__ __launch_bounds__(512, 2) void pass0_k(const float* __restrict__ x,
                                                  const float* __restrict__ W,
                                                  unsigned* __restrict__ xts,
                                                  float* __restrict__ sb)
{
    __shared__ float lds[16384];
    const int pb = blockIdx.x;
    const int lin = (pb & 7) * 30 + (pb >> 3);
    const int rch = lin / 10;
    const int c   = lin - rch * 10;
    const int t = threadIdx.x;
    const int w = t >> 6, l = t & 63;
    const int h = w >> 1, bp = w & 1;
    const int lo5 = l & 31, hi1 = l >> 5;
    const int r0 = rch * 48 + h * 12;

    float dum0[16], dum1[16];
    f32x16 acc0, acc1; float Z0, Z1;
    route_mainloop<0>(x, W, (uint4*)xts, c, r0, bp, lo5, hi1,
                      dum0, dum1, acc0, acc1, Z0, Z1);
    chunk_atomic_add<0>(acc0, acc1, Z0, Z1, t, l, h, bp, lo5, hi1,
                        lds, sb + (size_t)c * 4096, nullptr);
}

// ------------------------------------------------------------------
// fused12_k: routing iterations 1 and 2 in ONE kernel.
// Start: every block redundantly merges sb0 (16KB, dispatch-boundary
// visible) -> out0 fragments in registers. Phase 1 mainloop -> atomicAdd
// sb1/zb1 -> per-capsule spin barrier (cnt[c], proven handshake) ->
// redundant merge -> ov += out1. Phase 2 mainloop -> atomicAdd sb2/zb2;
// all blocks sign off cnt[NC+c]; only rch==0 blocks spin, merge, write dout.
// Intra-kernel cross-block traffic is agent-scope atomics only (coherence
// point) -> no reliance on cross-XCD L2 coherence. 240 blocks <= 256 CUs
// at >=1 block/CU -> all co-resident, spin cannot deadlock.
// ------------------------------------------------------------------
__global__ __launch_bounds__(512, 2) void fused12_k(const float* __restrict__ W,
                                                    unsigned* __restrict__ xts,
                                                    float* __restrict__ dout,
                                                    float* __restrict__ sb,
                                                    float* __restrict__ zb,
                                                    int* __restrict__ cnt)
{
    __shared__ float lds[16384];
    const int pb = blockIdx.x;
    const int lin = (pb & 7) * 30 + (pb >> 3);
    const int rch = lin / 10;
    const int c   = lin - rch * 10;
    const int t = threadIdx.x;
    const int w = t >> 6, l = t & 63;
    const int h = w >> 1, bp = w & 1;
    const int lo5 = l & 31, hi1 = l >> 5;
    const int r0 = rch * 48 + h * 12;
    uint4* xt4 = (uint4*)xts;

    float ov0[16], ov1[16], sv[8];

    // ---- out0 from sb0 (previous dispatch; normal loads) ----
    merge_squash<0, false>(sb + (size_t)c * 4096, nullptr, t, lds, sv);
#pragma unroll
    for (int j = 0; j < 16; ++j) {
        int orow = (j & 3) + 8 * (j >> 2) + 4 * hi1;
        float ffj = lds[5008 + orow];
        ov0[j] = lds[(bp * 64 + lo5) * 33 + orow] * ffj;
        ov1[j] = lds[(bp * 64 + 32 + lo5) * 33 + orow] * ffj;
    }

    // ---- phase 1: softmax(pred . out0) ----
    f32x16 acc0, acc1; float Z0, Z1;
    route_mainloop<1>(nullptr, W, xt4, c, r0, bp, lo5, hi1,
                      ov0, ov1, acc0, acc1, Z0, Z1);
    float* sc1 = sb + (size_t)(NC + c) * 4096;
    float* zc1 = zb + (size_t)c * 128;
    chunk_atomic_add<1>(acc0, acc1, Z0, Z1, t, l, h, bp, lo5, hi1, lds, sc1, zc1);

    // per-capsule barrier (adds drained by __syncthreads' vmcnt(0))
    __syncthreads();
    if (t == 0) {
        __hip_atomic_fetch_add(&cnt[c], 1, __ATOMIC_RELAXED, __HIP_MEMORY_SCOPE_AGENT);
        while (__hip_atomic_load(&cnt[c], __ATOMIC_RELAXED,
                                 __HIP_MEMORY_SCOPE_AGENT) < NCHK)
            __builtin_amdgcn_s_sleep(4);
    }
    __syncthreads();

    merge_squash<1, true>(sc1, zc1, t, lds, sv);
#pragma unroll
    for (int j = 0; j < 16; ++j) {
        int orow = (j & 3) + 8 * (j >> 2) + 4 * hi1;
        float ffj = lds[5008 + orow];
        ov0[j] += lds[(bp * 64 + lo5) * 33 + orow] * ffj;
        ov1[j] += lds[(bp * 64 + 32 + lo5) * 33 + orow] * ffj;
    }

    // ---- phase 2: softmax(pred . (out0+out1)) ----
    route_mainloop<1>(nullptr, W, xt4, c, r0, bp, lo5, hi1,
                      ov0, ov1, acc0, acc1, Z0, Z1);
    float* sc2 = sb + (size_t)(2 * NC + c) * 4096;
    float* zc2 = zb + (size_t)(NC + c) * 128;
    chunk_atomic_add<1>(acc0, acc1, Z0, Z1, t, l, h, bp, lo5, hi1, lds, sc2, zc2);

    __syncthreads();
    if (t == 0)
        __hip_atomic_fetch_add(&cnt[NC + c], 1, __ATOMIC_RELAXED,
                               __HIP_MEMORY_SCOPE_AGENT);
    if (rch != 0) return;          // non-writers retire
    if (t == 0) {
        while (__hip_atomic_load(&cnt[NC + c], __ATOMIC_RELAXED,
                                 __HIP_MEMORY_SCOPE_AGENT) < NCHK)
            __builtin_amdgcn_s_sleep(4);
    }
    __syncthreads();

    merge_squash<2, true>(sc2, zc2, t, lds, sv);
    const float ff2 = lds[5008 + (t & 31)];
#pragma unroll
    for (int k = 0; k < 8; ++k)
        dout[(size_t)c * 4096 + t + 512 * k] = sv[k] * ff2;
}

// ------------------------------------------------------------------
extern "C" void kernel_launch(void* const* d_in, const int* in_sizes, int n_in,
                              void* d_out, int out_size, void* d_ws, size_t ws_size,
                              hipStream_t stream)
{
    (void)in_sizes; (void)n_in; (void)out_size; (void)ws_size;
    const float* x = (const float*)d_in[0];
    const float* W = (const float*)d_in[1];
    float* wsf  = (float*)d_ws;
    float* outf = (float*)d_out;

    // ws layout (32-bit units):
    // xts 2,359,296 | sb 3x40,960 | zb 2x1,280 | cnt 32   (~9.9 MB)
    unsigned* xts = (unsigned*)d_ws;
    float* sb  = wsf + 2359296;
    float* zb  = sb + 3 * 40960;
    int*   cnt = (int*)(zb + 2 * 1280);

    // zero accumulators + counters (ws is poisoned to 0xAA once)
    hipMemsetAsync(sb, 0, (size_t)(3 * 40960 + 2 * 1280 + 32) * 4, stream);

    // iter 0: uniform; owner lanes emit xts bf16 planes; adds into sb0
    pass0_k<<<240, 512, 0, stream>>>(x, W, xts, sb);
    // iters 1+2 fused: in-kernel per-capsule barriers; writes d_out
    fused12_k<<<240, 512, 0, stream>>>(W, xts, outf, sb, zb, cnt);
}